// Round 7
// baseline (161.525 us; speedup 1.0000x reference)
//
#include <hip/hip_runtime.h>
#include <hip/hip_bf16.h>

// B=4 S=1024 D=1024 H=16 DH=64 -> flat M=4096, attention raw view [64][1024][64]

using u16 = unsigned short;
typedef __attribute__((ext_vector_type(8))) short bf16x8;
typedef __attribute__((ext_vector_type(4))) float f32x4;
typedef __attribute__((ext_vector_type(4))) u16  u16x4;
typedef __attribute__((ext_vector_type(8))) u16  u16x8;

#define AS1C(p) ((const __attribute__((address_space(1))) void*)(p))
#define AS3(p)  ((__attribute__((address_space(3))) void*)(p))

__device__ __forceinline__ u16 f2bf(float f) {
  union { float f; unsigned u; } v; v.f = f;
  unsigned u = v.u;
  return (u16)((u + 0x7fffu + ((u >> 16) & 1u)) >> 16);  // RNE
}

__device__ __forceinline__ f32x4 mfma16(bf16x8 a, bf16x8 b, f32x4 c) {
  return __builtin_amdgcn_mfma_f32_16x16x32_bf16(a, b, c, 0, 0, 0);
}

#define BARRIER() do { asm volatile("" ::: "memory"); __builtin_amdgcn_s_barrier(); asm volatile("" ::: "memory"); } while (0)

// ---------------- prep: fp32->bf16 for x and W's, concat biases ----------------
__global__ __launch_bounds__(256) void prep_kernel(
    const float* __restrict__ x,
    const float* __restrict__ wq, const float* __restrict__ wk,
    const float* __restrict__ wv, const float* __restrict__ wo,
    const float* __restrict__ bq, const float* __restrict__ bk, const float* __restrict__ bv,
    u16* __restrict__ xb, u16* __restrict__ wb, float* __restrict__ bc)
{
  int ch = blockIdx.x * 256 + threadIdx.x;
  if (ch < 2097152) {
    const float* src; u16* dst;
    if (ch < 1048576) { src = x + ch * 4; dst = xb + ch * 4; }
    else {
      int c2 = ch - 1048576;
      int wsel = c2 >> 18;
      int off  = c2 & 262143;
      const float* wsrc[4] = { wq, wk, wv, wo };
      src = wsrc[wsel] + off * 4;
      dst = wb + wsel * 1048576 + off * 4;
    }
    f32x4 v = *(const f32x4*)src;
    u16x4 o;
    o[0] = f2bf(v[0]); o[1] = f2bf(v[1]); o[2] = f2bf(v[2]); o[3] = f2bf(v[3]);
    *(u16x4*)dst = o;
  } else {
    int c3 = ch - 2097152;            // < 768
    int bsel = c3 >> 8, off = c3 & 255;
    const float* bsrc[3] = { bq, bk, bv };
    f32x4 v = *(const f32x4*)(bsrc[bsel] + off * 4);
    *(f32x4*)(bc + bsel * 1024 + off * 4) = v;
  }
}

// ---------------- QKV GEMM: 256x256 tile, BK=64, 8 waves, 4-phase/K-tile interleave ----------------
// Phases per tile t (slot d=t&1): P0{LDA m0-3 + LDB n01 (12 ds), stage A-h0(t+1)->d^1, bar,
// lgkm0, 16 MFMA m0-3xn01, bar} P1{LDB n23 (4), stage A-h1(t+1), ..., MFMA m0-3xn23}
// P2{LDA m4-7 (8), stage B-h0(t+2)->d, ..., MFMA m4-7xn23} P3{stage B-h1(t+2), vmcnt(4),
// bar, MFMA m4-7xn01, bar}.
// Ledger (per-wave, 2 loads/stage): one vmcnt(4)/tile leaves {B(t+2)} in flight; drains
// A(t+1) (issued P0/P1) + B(t+1) (issued t-1 P2/P3) -> all tile-(t+1) data certified before
// its P0 reads; barrier extends cross-wave. WAR: B-h stages at P2/P3 write slot d after all
// B(t) reads drained (issued P0/P1, lgkm0 each phase, barrier P1-end). A stages write d^1,
// read last by tile t-1 (done at its P3-end barrier). vmcnt never 0 until t>=14.
// LDS swizzle: byte ^= (row&7)<<4 (16B granule) -> af/bf ds_read_b128 2-way (free).
// Stage via pre-swizzled global source (involution), dest lane-linear for global_load_lds.
// Out: Q*0.125 | K | V^T[64bh][64dh][1024k] bf16; block map bm=bid&15 keeps the 4 writers
// of each V^T 128B line (bn in {8..11}, same bm) on one XCD (round-5 proven).
__global__ __launch_bounds__(512, 2) void gemm_qkv(
    const u16* __restrict__ A, const u16* __restrict__ Bw,
    const float* __restrict__ bias, u16* __restrict__ outb)
{
  __shared__ u16 As[2][2][8192];   // [slot][half][128*64]
  __shared__ u16 Bs[2][2][8192];

  const int K = 1024;
  int tid = threadIdx.x, w = tid >> 6, lane = tid & 63;
  int g = lane >> 4, lr = lane & 15;
  int wr = w >> 2, wc = w & 3;           // 2x4 wave grid; wave out = 128x64
  int bid = blockIdx.x;
  int bm = bid & 15, bn = bid >> 4;      // grid 192 = 16 x 12

  // staging geometry: half-tile = 128 rows x 64 cols; 1024 chunks of 16B; 2/thread
  int r0 = tid >> 3;                                  // rows r0 and r0+64
  int c0 = ((tid & 7) ^ (r0 & 7)) * 8;                // pre-swizzled source col (u16)
  const u16* Abase = A  + (size_t)(bm * 256) * K;
  const u16* Bbase = Bw + (size_t)(bn * 256) * K;

  auto stageA = [&](int slot, int h, int kt) {
    const u16* s0 = Abase + (size_t)(h * 128 + r0) * K + kt * 64 + c0;
    u16* dst = &As[slot][h][tid * 8];
    __builtin_amdgcn_global_load_lds(AS1C(s0),            AS3(dst),        16, 0, 0);
    __builtin_amdgcn_global_load_lds(AS1C(s0 + 64 * K),   AS3(dst + 4096), 16, 0, 0);
  };
  auto stageB = [&](int slot, int h, int kt) {
    const u16* s0 = Bbase + (size_t)(h * 128 + r0) * K + kt * 64 + c0;
    u16* dst = &Bs[slot][h][tid * 8];
    __builtin_amdgcn_global_load_lds(AS1C(s0),            AS3(dst),        16, 0, 0);
    __builtin_amdgcn_global_load_lds(AS1C(s0 + 64 * K),   AS3(dst + 4096), 16, 0, 0);
  };

  f32x4 acc[8][4] = {};
  bf16x8 af[4][2], bf[4][2];
  int rsw = (lr & 7) * 8;                 // u16-granule row swizzle

  auto LDA = [&](int slot, int mb) {
#pragma unroll
    for (int mm = 0; mm < 4; ++mm)
#pragma unroll
      for (int kk = 0; kk < 2; ++kk)
        af[mm][kk] = *(const bf16x8*)&As[slot][wr][(mb + mm) * 1024 + lr * 64 + ((kk * 32 + g * 8) ^ rsw)];
  };
  auto LDB = [&](int slot, int nb) {
#pragma unroll
    for (int nn = 0; nn < 2; ++nn)
#pragma unroll
      for (int kk = 0; kk < 2; ++kk)
        bf[nb + nn][kk] = *(const bf16x8*)&Bs[slot][wc >> 1][((wc & 1) * 64 + (nb + nn) * 16 + lr) * 64 + ((kk * 32 + g * 8) ^ rsw)];
  };
  auto MF = [&](int mb, int nb) {
    __builtin_amdgcn_s_setprio(1);
#pragma unroll
    for (int mm = 0; mm < 4; ++mm)
#pragma unroll
      for (int nn = 0; nn < 2; ++nn)
#pragma unroll
        for (int kk = 0; kk < 2; ++kk)
          acc[mb + mm][nb + nn] = mfma16(af[mm][kk], bf[nb + nn][kk], acc[mb + mm][nb + nn]);
    __builtin_amdgcn_s_setprio(0);
  };

  // prologue: A(0), B(0), B(1); vmcnt(4) leaves B(1) in flight (steady-state invariant)
  stageA(0, 0, 0); stageA(0, 1, 0);
  stageB(0, 0, 0); stageB(0, 1, 0);
  stageB(1, 0, 1); stageB(1, 1, 1);
  asm volatile("s_waitcnt vmcnt(4)" ::: "memory");
  BARRIER();

  for (int t = 0; t < 16; ++t) {
    int d = t & 1;
    // P0
    LDA(d, 0); LDB(d, 0);
    if (t + 1 < 16) stageA(d ^ 1, 0, t + 1);
    BARRIER();
    asm volatile("s_waitcnt lgkmcnt(0)" ::: "memory");
    __builtin_amdgcn_sched_barrier(0);
    MF(0, 0);
    BARRIER();
    // P1
    LDB(d, 2);
    if (t + 1 < 16) stageA(d ^ 1, 1, t + 1);
    BARRIER();
    asm volatile("s_waitcnt lgkmcnt(0)" ::: "memory");
    __builtin_amdgcn_sched_barrier(0);
    MF(0, 2);
    BARRIER();
    // P2
    LDA(d, 4);
    if (t + 2 < 16) stageB(d, 0, t + 2);
    BARRIER();
    asm volatile("s_waitcnt lgkmcnt(0)" ::: "memory");
    __builtin_amdgcn_sched_barrier(0);
    MF(4, 2);
    BARRIER();
    // P3
    if (t + 2 < 16) stageB(d, 1, t + 2);
    if (t < 14) { asm volatile("s_waitcnt vmcnt(4)" ::: "memory"); }
    else        { asm volatile("s_waitcnt vmcnt(0)" ::: "memory"); }
    BARRIER();
    __builtin_amdgcn_sched_barrier(0);
    MF(4, 0);
    BARRIER();
  }

  // epilogue: D layout col=lane&15, row=(lane>>4)*4+i
#pragma unroll
  for (int m = 0; m < 8; ++m) {
    int row0 = bm * 256 + wr * 128 + m * 16 + 4 * g;
#pragma unroll
    for (int n = 0; n < 4; ++n) {
      int col = bn * 256 + wc * 64 + n * 16 + lr;
#pragma unroll
      for (int i = 0; i < 4; ++i) {
        float v = acc[m][n][i] + bias[col];
        int r = row0 + i;
        if (col < 1024) {
          outb[(size_t)r * 1024 + col] = f2bf(v * 0.125f);               // Q (scale folded)
        } else if (col < 2048) {
          outb[4194304 + (size_t)r * 1024 + (col - 1024)] = f2bf(v);     // K
        } else {
          int c = col - 2048;
          // V^T[bh=r>>6][dh=c&63][k=(r&63)*16+(c>>6)]
          outb[8388608 + (size_t)(r >> 6) * 65536 + (size_t)(c & 63) * 1024
               + (r & 63) * 16 + (c >> 6)] = f2bf(v);
        }
      }
    }
  }
}

// ---------------- out-proj GEMM: 64x128 tile, BK=32, 4 waves, 3-buf counted pipeline ----------------
// Round-6 structure (proven), tile narrowed to 64 rows -> grid 512 (2 blocks/CU of TLP).
// 3 loads/tile (1 A + 2 B) -> steady vmcnt(3). out f32 = acc + bias + residual.
__global__ __launch_bounds__(256) void gemm_op(
    const u16* __restrict__ A, const u16* __restrict__ Bw,
    const float* __restrict__ bias, const float* __restrict__ resid,
    float* __restrict__ outf)
{
  __shared__ u16 As[3][2048];    // [64][32] per buffer
  __shared__ u16 Bs[3][4096];    // [128][32]

  const int K = 1024;
  int tid = threadIdx.x, w = tid >> 6, lane = tid & 63;
  int g = lane >> 4, lr = lane & 15;
  int wr = w >> 1, wcn = w & 1;
  int bid = blockIdx.x;
  int bm = bid & 63, bn = bid >> 6;      // grid 512 = 64 x 8

  // A: 256 chunks (1/thread); B: 512 chunks (2/thread); source pre-swizzled
  auto srcoff = [&](int ch) -> size_t {
    int r = ch >> 2, pc = ch & 3;
    int gc = pc ^ ((r >> 2) & 3);
    return (size_t)r * K + gc * 8;
  };
  const u16* aS0 = A  + (size_t)(bm * 64)  * K + srcoff(tid);
  const u16* bS0 = Bw + (size_t)(bn * 128) * K + srcoff(tid);
  const u16* bS1 = Bw + (size_t)(bn * 128) * K + srcoff(tid + 256);

  auto STAGE = [&](int buf, int kt) {
    __builtin_amdgcn_global_load_lds(AS1C(aS0 + kt * 32), AS3(&As[buf][tid * 8]),        16, 0, 0);
    __builtin_amdgcn_global_load_lds(AS1C(bS0 + kt * 32), AS3(&Bs[buf][tid * 8]),        16, 0, 0);
    __builtin_amdgcn_global_load_lds(AS1C(bS1 + kt * 32), AS3(&Bs[buf][2048 + tid * 8]), 16, 0, 0);
  };

  f32x4 acc[2][4] = {};
  int pc8 = (g ^ ((lr >> 2) & 3)) * 8;

  auto COMPUTE = [&](int buf) {
    bf16x8 af[2], bfr[4];
#pragma unroll
    for (int m = 0; m < 2; ++m)
      af[m] = *(const bf16x8*)&As[buf][(wr * 32 + m * 16 + lr) * 32 + pc8];
#pragma unroll
    for (int n = 0; n < 4; ++n)
      bfr[n] = *(const bf16x8*)&Bs[buf][(wcn * 64 + n * 16 + lr) * 32 + pc8];
    __builtin_amdgcn_s_setprio(1);
#pragma unroll
    for (int m = 0; m < 2; ++m)
#pragma unroll
      for (int n = 0; n < 4; ++n)
        acc[m][n] = mfma16(af[m], bfr[n], acc[m][n]);
    __builtin_amdgcn_s_setprio(0);
  };

  STAGE(0, 0); STAGE(1, 1);

  int sb = 2, cb = 0;
  for (int t = 0; t < 31; ++t) {
    asm volatile("s_waitcnt vmcnt(3)" ::: "memory");  // tile t landed; t+1 in flight
    __builtin_amdgcn_s_barrier();
    asm volatile("" ::: "memory");
    if (t < 30) {
      STAGE(sb, t + 2);
      if (++sb == 3) sb = 0;
    }
    COMPUTE(cb);
    if (++cb == 3) cb = 0;
  }
  asm volatile("s_waitcnt vmcnt(0)" ::: "memory");
  __builtin_amdgcn_s_barrier();
  asm volatile("" ::: "memory");
  COMPUTE(cb);

#pragma unroll
  for (int m = 0; m < 2; ++m) {
    int row0 = bm * 64 + wr * 32 + m * 16 + 4 * g;
#pragma unroll
    for (int n = 0; n < 4; ++n) {
      int col = bn * 128 + wcn * 64 + n * 16 + lr;
#pragma unroll
      for (int i = 0; i < 4; ++i) {
        size_t idx = (size_t)(row0 + i) * 1024 + col;
        outf[idx] = acc[m][n][i] + bias[col] + resid[idx];
      }
    }
  }
}

// ---------------- flash attention: raw view [64][1024][64], KV-tile 64, 8 waves ----------------
__global__ __launch_bounds__(512) void attn_kernel(
    const u16* __restrict__ Qb, const u16* __restrict__ Kb,
    const u16* __restrict__ Vtb, u16* __restrict__ Ob)
{
  __shared__ u16 Ks[2][64 * 64];    // [kc][d], chunk-swizzled: LDS[r][c] = glob chunk c^(r&7)
  __shared__ u16 Vts[2][64 * 64];   // [dh][k], same swizzle
  __shared__ u16 Ps[8][16 * 72];    // per-wave P [16 q][64 k], pad 72

  int blk = blockIdx.x;
  int bh = blk & 63, qt = blk >> 6;          // same-head blocks share XCD L2
  int tid = threadIdx.x, wid = tid >> 6, lane = tid & 63;
  int g = lane >> 4, lr = lane & 15;

  const u16* Qp = Qb  + (size_t)bh * 65536;
  const u16* Kp = Kb  + (size_t)bh * 65536;
  const u16* Vp = Vtb + (size_t)bh * 65536;

  // Q fragments: rows qt*128 + wid*16 + lr
  bf16x8 qf[2];
#pragma unroll
  for (int f = 0; f < 2; ++f)
    qf[f] = *(const bf16x8*)&Qp[(size_t)(qt * 128 + wid * 16 + lr) * 64 + f * 32 + 8 * g];

  f32x4 oacc[4] = {};
  float mrow[4], lrowv[4];
#pragma unroll
  for (int i = 0; i < 4; ++i) { mrow[i] = -1e30f; lrowv[i] = 0.f; }

  // staging addresses (512 chunks of 16B per buffer, one instr per thread)
  int kc  = tid >> 3, scc = tid & 7;
  const u16* gkBase = Kp + (size_t)kc * 64 + (size_t)(scc ^ (kc & 7)) * 8;   // + kt*64*64
  const u16* gvBase = Vp + (size_t)kc * 1024 + (size_t)(scc ^ (kc & 7)) * 8; // row=dh, + kt*64

#define STAGE_ATTN(b, kt) do { \
    __builtin_amdgcn_global_load_lds(AS1C(gkBase + (size_t)(kt) * 4096), AS3(&Ks[b][tid * 8]),  16, 0, 0); \
    __builtin_amdgcn_global_load_lds(AS1C(gvBase + (kt) * 64),           AS3(&Vts[b][tid * 8]), 16, 0, 0); \
  } while (0)

  STAGE_ATTN(0, 0);
  __syncthreads();
  int cur = 0;

  for (int kt = 0; kt < 16; ++kt) {
    if (kt + 1 < 16) STAGE_ATTN(cur ^ 1, kt + 1);

    // --- S = Q K^T (Q pre-scaled). s[n][i] = S[4g+i][n*16+lr]
    f32x4 s[4];
#pragma unroll
    for (int n = 0; n < 4; ++n) {
      f32x4 z = { 0.f, 0.f, 0.f, 0.f };
      int kr = n * 16 + lr;
#pragma unroll
      for (int f = 0; f < 2; ++f) {
        bf16x8 kb = *(const bf16x8*)&Ks[cur][kr * 64 + (((f * 4 + g) ^ (kr & 7)) * 8)];
        z = mfma16(qf[f], kb, z);
      }
      s[n] = z;
    }

    // --- online softmax (row = 4g+i, spread over 16 lr-lanes)
    float corr[4], pvv[4][4];
#pragma unroll
    for (int i = 0; i < 4; ++i) {
      float tm = fmaxf(fmaxf(s[0][i], s[1][i]), fmaxf(s[2][i], s[3][i]));
#pragma unroll
      for (int ms = 1; ms < 16; ms <<= 1) tm = fmaxf(tm, __shfl_xor(tm, ms));
      float mn = fmaxf(mrow[i], tm);
      corr[i] = __expf(mrow[i] - mn);
      float rs = 0.f;
#pragma unroll
      for (int n = 0; n < 4; ++n) {
        float p = __expf(s[n][i] - mn);
        pvv[n][i] = p; rs += p;
      }
#pragma unroll
      for (int ms = 1; ms < 16; ms <<= 1) rs += __shfl_xor(rs, ms);
      lrowv[i] = lrowv[i] * corr[i] + rs;
      mrow[i] = mn;
    }
#pragma unroll
    for (int nd = 0; nd < 4; ++nd) {
      f32x4 o = oacc[nd];
      o[0] *= corr[0]; o[1] *= corr[1]; o[2] *= corr[2]; o[3] *= corr[3];
      oacc[nd] = o;
    }

    // --- P -> LDS (wave-local)
#pragma unroll
    for (int n = 0; n < 4; ++n)
#pragma unroll
      for (int i = 0; i < 4; ++i)
        Ps[wid][(4 * g + i) * 72 + n * 16 + lr] = f2bf(pvv[n][i]);
    asm volatile("s_waitcnt lgkmcnt(0)" ::: "memory");

    // --- PV: ctx[q][d] += P[q][k] V^T[d][k]
#pragma unroll
    for (int f = 0; f < 2; ++f) {
      bf16x8 pa = *(const bf16x8*)&Ps[wid][lr * 72 + f * 32 + 8 * g];
#pragma unroll
      for (int nd = 0; nd < 4; ++nd) {
        int dr = nd * 16 + lr;
        bf16x8 vb = *(const bf16x8*)&Vts[cur][dr * 64 + (((f * 4 + g) ^ (dr & 7)) * 8)];
        oacc[nd] = mfma16(pa, vb, oacc[nd]);
      }
    }
    __syncthreads();   // next tile landed (vmcnt0); reads of cur done (lgkm0)
    cur ^= 1;
  }

  // epilogue: ctx = oacc / l
  u16* Op = Ob + (size_t)bh * 65536 + (size_t)(qt * 128 + wid * 16) * 64;
#pragma unroll
  for (int nd = 0; nd < 4; ++nd)
#pragma unroll
    for (int i = 0; i < 4; ++i)
      Op[(4 * g + i) * 64 + nd * 16 + lr] = f2bf(oacc[nd][i] / lrowv[i]);
}

// ---------------- LayerNorm in-place over rows of out [4096][1024] ----------------
__global__ __launch_bounds__(256) void ln_kernel(
    float* __restrict__ out, const float* __restrict__ gamma, const float* __restrict__ beta)
{
  int row = blockIdx.x, tid = threadIdx.x;
  int lane = tid & 63, wid = tid >> 6;
  f32x4 v = *(const f32x4*)&out[(size_t)row * 1024 + tid * 4];
  float s = v[0] + v[1] + v[2] + v[3];
  float q = v[0] * v[0] + v[1] * v[1] + v[2] * v[2] + v[3] * v[3];
#pragma unroll
  for (int ms = 1; ms < 64; ms <<= 1) { s += __shfl_xor(s, ms); q += __shfl_xor(q, ms); }
  __shared__ float red[8];
  if (lane == 0) { red[wid] = s; red[wid + 4] = q; }
  __syncthreads();
  s = red[0] + red[1] + red[2] + red[3];
  q = red[4] + red[5] + red[6] + red[7];
  float mu = s * (1.f / 1024.f);
  float var = q * (1.f / 1024.f) - mu * mu;
  float inv = rsqrtf(var + 1e-5f);
  f32x4 g4 = *(const f32x4*)&gamma[tid * 4];
  f32x4 b4 = *(const f32x4*)&beta[tid * 4];
  f32x4 o;
#pragma unroll
  for (int j = 0; j < 4; ++j) o[j] = (v[j] - mu) * inv * g4[j] + b4[j];
  *(f32x4*)&out[(size_t)row * 1024 + tid * 4] = o;
}

// ---------------- launch ----------------
extern "C" void kernel_launch(void* const* d_in, const int* in_sizes, int n_in,
                              void* d_out, int out_size, void* d_ws, size_t ws_size,
                              hipStream_t stream) {
  const float* x     = (const float*)d_in[0];
  const float* Wq    = (const float*)d_in[1];
  const float* bq    = (const float*)d_in[2];
  const float* Wk    = (const float*)d_in[3];
  const float* bk    = (const float*)d_in[4];
  const float* Wv    = (const float*)d_in[5];
  const float* bv    = (const float*)d_in[6];
  const float* Wo    = (const float*)d_in[7];
  const float* bo    = (const float*)d_in[8];
  const float* gamma = (const float*)d_in[9];
  const float* beta  = (const float*)d_in[10];
  float* out = (float*)d_out;

  char* ws = (char*)d_ws;
  u16*   xb  = (u16*)ws;                                   // 8MB  [4096][1024] bf16 (reused as ctx)
  u16*   wb  = (u16*)(ws + (8u << 20));                    // 8MB  Wq|Wk|Wv|Wo bf16
  float* bc  = (float*)(ws + (16u << 20));                 // 12KB bq|bk|bv
  u16*   qkv = (u16*)(ws + (16u << 20) + 16384);           // 24MB Q | K | V^T bf16
  u16*   ctx = xb;                                         // overlay: xb dead after QKV GEMM

  prep_kernel<<<8195, 256, 0, stream>>>(x, Wq, Wk, Wv, Wo, bq, bk, bv, xb, wb, bc);

  // QKV: M=4096 x N=3072, 256^2 tiles -> grid 192 (bm=bid&15, bn=bid>>4)
  gemm_qkv<<<192, 512, 0, stream>>>(xb, wb, bc, qkv);

  attn_kernel<<<512, 512, 0, stream>>>(qkv, qkv + 4194304, qkv + 8388608, ctx);

  // out-proj: M=4096 x N=1024, 64x128 tiles -> grid 512
  gemm_op<<<512, 256, 0, stream>>>(ctx, wb + 3 * 1048576, bo, x, out);

  ln_kernel<<<4096, 256, 0, stream>>>(out, gamma, beta);
}

// Round 8
// 134.260 us; speedup vs baseline: 1.2031x; 1.2031x over previous
//
#include <hip/hip_runtime.h>
#include <hip/hip_bf16.h>

// B=4 S=1024 D=1024 H=16 DH=64 -> flat M=4096, attention raw view [64][1024][64]

using u16 = unsigned short;
using u32 = unsigned int;
typedef __attribute__((ext_vector_type(8)))  short bf16x8;
typedef __attribute__((ext_vector_type(4)))  float f32x4;
typedef __attribute__((ext_vector_type(16))) float f32x16;
typedef __attribute__((ext_vector_type(4)))  u16  u16x4;
typedef __attribute__((ext_vector_type(8)))  u16  u16x8;

#define AS1C(p) ((const __attribute__((address_space(1))) void*)(p))
#define AS3(p)  ((__attribute__((address_space(3))) void*)(p))

__device__ __forceinline__ u16 f2bf(float f) {
  union { float f; unsigned u; } v; v.f = f;
  unsigned u = v.u;
  return (u16)((u + 0x7fffu + ((u >> 16) & 1u)) >> 16);  // RNE
}

__device__ __forceinline__ f32x4 mfma16(bf16x8 a, bf16x8 b, f32x4 c) {
  return __builtin_amdgcn_mfma_f32_16x16x32_bf16(a, b, c, 0, 0, 0);
}
__device__ __forceinline__ f32x16 mfma32(bf16x8 a, bf16x8 b, f32x16 c) {
  return __builtin_amdgcn_mfma_f32_32x32x16_bf16(a, b, c, 0, 0, 0);
}

// ---------------- prep: fp32->bf16 for x and W's, concat biases ----------------
__global__ __launch_bounds__(256) void prep_kernel(
    const float* __restrict__ x,
    const float* __restrict__ wq, const float* __restrict__ wk,
    const float* __restrict__ wv, const float* __restrict__ wo,
    const float* __restrict__ bq, const float* __restrict__ bk, const float* __restrict__ bv,
    u16* __restrict__ xb, u16* __restrict__ wb, float* __restrict__ bc)
{
  int ch = blockIdx.x * 256 + threadIdx.x;
  if (ch < 2097152) {
    const float* src; u16* dst;
    if (ch < 1048576) { src = x + ch * 4; dst = xb + ch * 4; }
    else {
      int c2 = ch - 1048576;
      int wsel = c2 >> 18;
      int off  = c2 & 262143;
      const float* wsrc[4] = { wq, wk, wv, wo };
      src = wsrc[wsel] + off * 4;
      dst = wb + wsel * 1048576 + off * 4;
    }
    f32x4 v = *(const f32x4*)src;
    u16x4 o;
    o[0] = f2bf(v[0]); o[1] = f2bf(v[1]); o[2] = f2bf(v[2]); o[3] = f2bf(v[3]);
    *(u16x4*)dst = o;
  } else {
    int c3 = ch - 2097152;            // < 768
    int bsel = c3 >> 8, off = c3 & 255;
    const float* bsrc[3] = { bq, bk, bv };
    f32x4 v = *(const f32x4*)(bsrc[bsel] + off * 4);
    *(f32x4*)(bc + bsel * 1024 + off * 4) = v;
  }
}

// ---------------- QKV GEMM: round-6 proven (60.5us): 128x128, BK=32, 3-buf counted vmcnt ----------------
// Per K-step: vmcnt(4) -> s_barrier -> STAGE(t+2) -> COMPUTE(t). 48KB LDS -> 3 blocks/CU.
// Block map bm=(bid&7)+8*((bid>>3)&3), bn=bid>>5 keeps all 8 writers of each V^T 128B line
// on one XCD (round-5 proven; avoids 3x write amplification).
__global__ __launch_bounds__(256) void gemm_qkv(
    const u16* __restrict__ A, const u16* __restrict__ Bw,
    const float* __restrict__ bias, u16* __restrict__ outb)
{
  __shared__ u16 As[3][4096];
  __shared__ u16 Bs[3][4096];

  const int K = 1024;
  int tid = threadIdx.x, w = tid >> 6, lane = tid & 63;
  int g = lane >> 4, lr = lane & 15;
  int wr = w >> 1, wcn = w & 1;

  int bid = blockIdx.x;
  int bm = (bid & 7) + 8 * ((bid >> 3) & 3);
  int bn = bid >> 5;

  int ch0 = tid, ch1 = tid + 256;
  auto srcoff = [&](int ch) -> size_t {
    int r = ch >> 2, pc = ch & 3;
    int gc = pc ^ ((r >> 2) & 3);        // source pre-swizzle (involution)
    return (size_t)r * K + gc * 8;
  };
  const u16* aS0 = A  + (size_t)(bm * 128) * K + srcoff(ch0);
  const u16* aS1 = A  + (size_t)(bm * 128) * K + srcoff(ch1);
  const u16* bS0 = Bw + (size_t)(bn * 128) * K + srcoff(ch0);
  const u16* bS1 = Bw + (size_t)(bn * 128) * K + srcoff(ch1);
  int lo0 = ch0 * 8, lo1 = ch1 * 8;

  auto STAGE = [&](int buf, int kt) {
    __builtin_amdgcn_global_load_lds(AS1C(aS0 + kt * 32), AS3(&As[buf][lo0]), 16, 0, 0);
    __builtin_amdgcn_global_load_lds(AS1C(aS1 + kt * 32), AS3(&As[buf][lo1]), 16, 0, 0);
    __builtin_amdgcn_global_load_lds(AS1C(bS0 + kt * 32), AS3(&Bs[buf][lo0]), 16, 0, 0);
    __builtin_amdgcn_global_load_lds(AS1C(bS1 + kt * 32), AS3(&Bs[buf][lo1]), 16, 0, 0);
  };

  f32x4 acc[4][4] = {};
  int pc8 = (g ^ ((lr >> 2) & 3)) * 8;   // swizzled read chunk

  auto COMPUTE = [&](int buf) {
    bf16x8 af[4], bfr[4];
#pragma unroll
    for (int m = 0; m < 4; ++m)
      af[m] = *(const bf16x8*)&As[buf][(wr * 64 + m * 16 + lr) * 32 + pc8];
#pragma unroll
    for (int n = 0; n < 4; ++n)
      bfr[n] = *(const bf16x8*)&Bs[buf][(wcn * 64 + n * 16 + lr) * 32 + pc8];
    __builtin_amdgcn_s_setprio(1);
#pragma unroll
    for (int m = 0; m < 4; ++m)
#pragma unroll
      for (int n = 0; n < 4; ++n)
        acc[m][n] = mfma16(af[m], bfr[n], acc[m][n]);
    __builtin_amdgcn_s_setprio(0);
  };

  STAGE(0, 0); STAGE(1, 1);

  int sb = 2, cb = 0;
  for (int t = 0; t < 31; ++t) {
    asm volatile("s_waitcnt vmcnt(4)" ::: "memory");  // tile t landed; t+1 in flight
    __builtin_amdgcn_s_barrier();
    asm volatile("" ::: "memory");
    if (t < 30) {
      STAGE(sb, t + 2);
      if (++sb == 3) sb = 0;
    }
    COMPUTE(cb);
    if (++cb == 3) cb = 0;
  }
  asm volatile("s_waitcnt vmcnt(0)" ::: "memory");
  __builtin_amdgcn_s_barrier();
  asm volatile("" ::: "memory");
  COMPUTE(cb);

  // epilogue: D layout col=lane&15, row=(lane>>4)*4+i
#pragma unroll
  for (int m = 0; m < 4; ++m) {
    int row0 = bm * 128 + wr * 64 + m * 16 + 4 * g;
#pragma unroll
    for (int n = 0; n < 4; ++n) {
      int col = bn * 128 + wcn * 64 + n * 16 + lr;
#pragma unroll
      for (int i = 0; i < 4; ++i) {
        float v = acc[m][n][i] + bias[col];
        int r = row0 + i;
        if (col < 1024) {
          outb[(size_t)r * 1024 + col] = f2bf(v * 0.125f);               // Q (scale folded)
        } else if (col < 2048) {
          outb[4194304 + (size_t)r * 1024 + (col - 1024)] = f2bf(v);     // K
        } else {
          int c = col - 2048;
          // V^T[bh=r>>6][dh=c&63][k=(r&63)*16+(c>>6)]
          outb[8388608 + (size_t)(r >> 6) * 65536 + (size_t)(c & 63) * 1024
               + (r & 63) * 16 + (c >> 6)] = f2bf(v);
        }
      }
    }
  }
}

// ---------------- out-proj GEMM: 64x128 tile, BK=32, 4 waves, 3-buf counted pipeline ----------------
__global__ __launch_bounds__(256) void gemm_op(
    const u16* __restrict__ A, const u16* __restrict__ Bw,
    const float* __restrict__ bias, const float* __restrict__ resid,
    float* __restrict__ outf)
{
  __shared__ u16 As[3][2048];    // [64][32] per buffer
  __shared__ u16 Bs[3][4096];    // [128][32]

  const int K = 1024;
  int tid = threadIdx.x, w = tid >> 6, lane = tid & 63;
  int g = lane >> 4, lr = lane & 15;
  int wr = w >> 1, wcn = w & 1;
  int bid = blockIdx.x;
  int bm = bid & 63, bn = bid >> 6;      // grid 512 = 64 x 8

  auto srcoff = [&](int ch) -> size_t {
    int r = ch >> 2, pc = ch & 3;
    int gc = pc ^ ((r >> 2) & 3);
    return (size_t)r * K + gc * 8;
  };
  const u16* aS0 = A  + (size_t)(bm * 64)  * K + srcoff(tid);
  const u16* bS0 = Bw + (size_t)(bn * 128) * K + srcoff(tid);
  const u16* bS1 = Bw + (size_t)(bn * 128) * K + srcoff(tid + 256);

  auto STAGE = [&](int buf, int kt) {
    __builtin_amdgcn_global_load_lds(AS1C(aS0 + kt * 32), AS3(&As[buf][tid * 8]),        16, 0, 0);
    __builtin_amdgcn_global_load_lds(AS1C(bS0 + kt * 32), AS3(&Bs[buf][tid * 8]),        16, 0, 0);
    __builtin_amdgcn_global_load_lds(AS1C(bS1 + kt * 32), AS3(&Bs[buf][2048 + tid * 8]), 16, 0, 0);
  };

  f32x4 acc[2][4] = {};
  int pc8 = (g ^ ((lr >> 2) & 3)) * 8;

  auto COMPUTE = [&](int buf) {
    bf16x8 af[2], bfr[4];
#pragma unroll
    for (int m = 0; m < 2; ++m)
      af[m] = *(const bf16x8*)&As[buf][(wr * 32 + m * 16 + lr) * 32 + pc8];
#pragma unroll
    for (int n = 0; n < 4; ++n)
      bfr[n] = *(const bf16x8*)&Bs[buf][(wcn * 64 + n * 16 + lr) * 32 + pc8];
    __builtin_amdgcn_s_setprio(1);
#pragma unroll
    for (int m = 0; m < 2; ++m)
#pragma unroll
      for (int n = 0; n < 4; ++n)
        acc[m][n] = mfma16(af[m], bfr[n], acc[m][n]);
    __builtin_amdgcn_s_setprio(0);
  };

  STAGE(0, 0); STAGE(1, 1);

  int sb = 2, cb = 0;
  for (int t = 0; t < 31; ++t) {
    asm volatile("s_waitcnt vmcnt(3)" ::: "memory");
    __builtin_amdgcn_s_barrier();
    asm volatile("" ::: "memory");
    if (t < 30) {
      STAGE(sb, t + 2);
      if (++sb == 3) sb = 0;
    }
    COMPUTE(cb);
    if (++cb == 3) cb = 0;
  }
  asm volatile("s_waitcnt vmcnt(0)" ::: "memory");
  __builtin_amdgcn_s_barrier();
  asm volatile("" ::: "memory");
  COMPUTE(cb);

#pragma unroll
  for (int m = 0; m < 2; ++m) {
    int row0 = bm * 64 + wr * 32 + m * 16 + 4 * g;
#pragma unroll
    for (int n = 0; n < 4; ++n) {
      int col = bn * 128 + wcn * 64 + n * 16 + lr;
#pragma unroll
      for (int i = 0; i < 4; ++i) {
        size_t idx = (size_t)(row0 + i) * 1024 + col;
        outf[idx] = acc[m][n][i] + bias[col] + resid[idx];
      }
    }
  }
}

// ---------------- flash attention, 32x32 MFMA, swapped operands, in-register softmax ----------------
// View [64 bh][1024 k][64 d]. 2 waves/block, 32 q/wave, KV-tile 64, dbuf staging (as proven).
// Swapped QK^T: S^T = mfma32(A=K rows, B=Q rows): D[row=k_local][col=q=lane&31];
//   lane holds 32 S-values, ALL for its own q; k_local32(reg r) = (r&3)+8*(r>>2)+4*hi (hi=lane>>5).
// Softmax: in-lane tree (31 fmax / 31 add) + ONE shfl_xor(32). No LDS, no barrier.
// P->PV B-fragment (B[col=q][k]=P[q][k], lane needs k = s*16+8*hi+j, j=0..7 for step s):
//   pack s2 pairs to bf16: w[r1][p] = {k=4hi+8r1+2p, +1}; per step (t=s&1):
//   word0,1 = hi ? partner w[2t+1][p] : own w[2t][p]      (k = 16t+8hi+{0..3})
//   word2,3 = hi ? own w[2t+1][p-2]   : partner w[2t][p-2] (k = 16t+8hi+{4..7})
//   partner = shfl_xor(.,32). Verified index-by-index for both hi classes.
// PV: O^T = mfma32(A=V^T rows (d), B=P) -> oacc[dt][r]: col=q, row d_local=(r&3)+8*(r>>2)+4hi.
__global__ __launch_bounds__(128) void attn_kernel(
    const u16* __restrict__ Qb, const u16* __restrict__ Kb,
    const u16* __restrict__ Vtb, u16* __restrict__ Ob)
{
  __shared__ u16 Ks[2][4096];    // [k_local 64][d 64], 16B-chunk XOR swizzle c^(r&7)
  __shared__ u16 Vts[2][4096];   // [d 64][k_local 64], same swizzle

  int blk = blockIdx.x;
  int bh = blk & 63, qt = blk >> 6;          // same-head blocks share XCD L2
  int tid = threadIdx.x, wid = tid >> 6, lane = tid & 63;
  int l31 = lane & 31, hi = lane >> 5;

  const u16* Qp = Qb  + (size_t)bh * 65536;
  const u16* Kp = Kb  + (size_t)bh * 65536;
  const u16* Vp = Vtb + (size_t)bh * 65536;

  int q = qt * 64 + wid * 32 + l31;

  // Q as B-operand: lane holds Q[q][k-dims (hi*8..+8) within each 16-d step s]
  bf16x8 qf[4];
#pragma unroll
  for (int s = 0; s < 4; ++s)
    qf[s] = *(const bf16x8*)&Qp[(size_t)q * 64 + s * 16 + hi * 8];

  f32x16 oacc[2] = {};
  float mrow = -3e38f, lrow = 0.f;

  // staging: 512 chunks of 16B per buffer; 128 threads -> 4 chunks each per buffer
  const u16* gk[4]; const u16* gv[4];
#pragma unroll
  for (int j = 0; j < 4; ++j) {
    int ch = tid + 128 * j;
    int kc = ch >> 3, scc = ch & 7;
    int sc = scc ^ (kc & 7);                     // pre-swizzled source chunk
    gk[j] = Kp + (size_t)kc * 64   + sc * 8;     // + kt*4096
    gv[j] = Vp + (size_t)kc * 1024 + sc * 8;     // row=dh, + kt*64
  }

#define STAGE_A(b, kt) do { \
  _Pragma("unroll") \
  for (int j = 0; j < 4; ++j) { \
    int ch = tid + 128 * j; \
    __builtin_amdgcn_global_load_lds(AS1C(gk[j] + (size_t)(kt) * 4096), AS3(&Ks[b][ch * 8]),  16, 0, 0); \
    __builtin_amdgcn_global_load_lds(AS1C(gv[j] + (kt) * 64),           AS3(&Vts[b][ch * 8]), 16, 0, 0); \
  } } while (0)

  STAGE_A(0, 0);
  __syncthreads();
  int cur = 0;

  for (int kt = 0; kt < 16; ++kt) {
    if (kt + 1 < 16) STAGE_A(cur ^ 1, kt + 1);

    // --- S^T = K Q^T (Q pre-scaled by 1/8)
    f32x16 s2[2];
#pragma unroll
    for (int ks = 0; ks < 2; ++ks) {
      f32x16 z = {};
      int row = ks * 32 + l31;
      int rx = (row & 7);
#pragma unroll
      for (int s = 0; s < 4; ++s) {
        bf16x8 kb = *(const bf16x8*)&Ks[cur][row * 64 + (((2 * s + hi) ^ rx) * 8)];
        z = mfma32(kb, qf[s], z);
      }
      s2[ks] = z;
    }

    // --- online softmax, fully in-register (lane owns row q)
    float tv[16];
#pragma unroll
    for (int r = 0; r < 16; ++r) tv[r] = fmaxf(s2[0][r], s2[1][r]);
#pragma unroll
    for (int st = 8; st > 0; st >>= 1)
#pragma unroll
      for (int r = 0; r < st; ++r) tv[r] = fmaxf(tv[r], tv[r + st]);
    float tm = fmaxf(tv[0], __shfl_xor(tv[0], 32));
    float mn = fmaxf(mrow, tm);
    float corr = __expf(mrow - mn);

    float sv[16];
#pragma unroll
    for (int r = 0; r < 16; ++r) {
      s2[0][r] = __expf(s2[0][r] - mn);
      s2[1][r] = __expf(s2[1][r] - mn);
      sv[r] = s2[0][r] + s2[1][r];
    }
#pragma unroll
    for (int st = 8; st > 0; st >>= 1)
#pragma unroll
      for (int r = 0; r < st; ++r) sv[r] += sv[r + st];
    float rs = sv[0] + __shfl_xor(sv[0], 32);
    lrow = lrow * corr + rs;
    mrow = mn;

    // --- rescale O
#pragma unroll
    for (int dt = 0; dt < 2; ++dt)
#pragma unroll
      for (int r = 0; r < 16; ++r) oacc[dt][r] *= corr;

    // --- pack P to bf16 pairs: w[ks][r1][p] = {k=4hi+8r1+2p, +1}
    u32 wpk[2][4][2];
#pragma unroll
    for (int ks = 0; ks < 2; ++ks)
#pragma unroll
      for (int r1 = 0; r1 < 4; ++r1)
#pragma unroll
        for (int p = 0; p < 2; ++p)
          wpk[ks][r1][p] = (u32)f2bf(s2[ks][4 * r1 + 2 * p])
                         | ((u32)f2bf(s2[ks][4 * r1 + 2 * p + 1]) << 16);

    // --- PV: 4 k-steps of 16; build pb via one hi/lo exchange
#pragma unroll
    for (int s = 0; s < 4; ++s) {
      int ks = s >> 1, t = s & 1;
      u32 a0 = wpk[ks][2 * t][0],     a1 = wpk[ks][2 * t][1];
      u32 b0 = wpk[ks][2 * t + 1][0], b1 = wpk[ks][2 * t + 1][1];
      u32 sa0 = (u32)__shfl_xor((int)a0, 32), sa1 = (u32)__shfl_xor((int)a1, 32);
      u32 sb0 = (u32)__shfl_xor((int)b0, 32), sb1 = (u32)__shfl_xor((int)b1, 32);
      union { u32 u[4]; bf16x8 v; } pb;
      pb.u[0] = hi ? sb0 : a0;
      pb.u[1] = hi ? sb1 : a1;
      pb.u[2] = hi ? b0 : sa0;
      pb.u[3] = hi ? b1 : sa1;
#pragma unroll
      for (int dt = 0; dt < 2; ++dt) {
        int row = dt * 32 + l31;
        bf16x8 vb = *(const bf16x8*)&Vts[cur][row * 64 + (((2 * s + hi) ^ (row & 7)) * 8)];
        oacc[dt] = mfma32(vb, pb.v, oacc[dt]);
      }
    }

    __syncthreads();   // next tile landed (vmcnt0); reads of cur done (lgkm0)
    cur ^= 1;
  }

  // epilogue: ctx[q][d] = O^T[d][q] / lrow ; d_local(reg r) = (r&3)+8*(r>>2)+4hi
  float inv = 1.f / lrow;
  u16* Op = Ob + (size_t)bh * 65536 + (size_t)q * 64;
#pragma unroll
  for (int dt = 0; dt < 2; ++dt)
#pragma unroll
    for (int rq = 0; rq < 4; ++rq) {
      int d0 = dt * 32 + 8 * rq + 4 * hi;
      u16x4 o4;
#pragma unroll
      for (int rr = 0; rr < 4; ++rr) o4[rr] = f2bf(oacc[dt][4 * rq + rr] * inv);
      *(u16x4*)&Op[d0] = o4;
    }
}

// ---------------- LayerNorm in-place over rows of out [4096][1024] ----------------
__global__ __launch_bounds__(256) void ln_kernel(
    float* __restrict__ out, const float* __restrict__ gamma, const float* __restrict__ beta)
{
  int row = blockIdx.x, tid = threadIdx.x;
  int lane = tid & 63, wid = tid >> 6;
  f32x4 v = *(const f32x4*)&out[(size_t)row * 1024 + tid * 4];
  float s = v[0] + v[1] + v[2] + v[3];
  float q = v[0] * v[0] + v[1] * v[1] + v[2] * v[2] + v[3] * v[3];
#pragma unroll
  for (int ms = 1; ms < 64; ms <<= 1) { s += __shfl_xor(s, ms); q += __shfl_xor(q, ms); }
  __shared__ float red[8];
  if (lane == 0) { red[wid] = s; red[wid + 4] = q; }
  __syncthreads();
  s = red[0] + red[1] + red[2] + red[3];
  q = red[4] + red[5] + red[6] + red[7];
  float mu = s * (1.f / 1024.f);
  float var = q * (1.f / 1024.f) - mu * mu;
  float inv = rsqrtf(var + 1e-5f);
  f32x4 g4 = *(const f32x4*)&gamma[tid * 4];
  f32x4 b4 = *(const f32x4*)&beta[tid * 4];
  f32x4 o;
#pragma unroll
  for (int j = 0; j < 4; ++j) o[j] = (v[j] - mu) * inv * g4[j] + b4[j];
  *(f32x4*)&out[(size_t)row * 1024 + tid * 4] = o;
}

// ---------------- launch ----------------
extern "C" void kernel_launch(void* const* d_in, const int* in_sizes, int n_in,
                              void* d_out, int out_size, void* d_ws, size_t ws_size,
                              hipStream_t stream) {
  const float* x     = (const float*)d_in[0];
  const float* Wq    = (const float*)d_in[1];
  const float* bq    = (const float*)d_in[2];
  const float* Wk    = (const float*)d_in[3];
  const float* bk    = (const float*)d_in[4];
  const float* Wv    = (const float*)d_in[5];
  const float* bv    = (const float*)d_in[6];
  const float* Wo    = (const float*)d_in[7];
  const float* bo    = (const float*)d_in[8];
  const float* gamma = (const float*)d_in[9];
  const float* beta  = (const float*)d_in[10];
  float* out = (float*)d_out;

  char* ws = (char*)d_ws;
  u16*   xb  = (u16*)ws;                                   // 8MB  [4096][1024] bf16 (reused as ctx)
  u16*   wb  = (u16*)(ws + (8u << 20));                    // 8MB  Wq|Wk|Wv|Wo bf16
  float* bc  = (float*)(ws + (16u << 20));                 // 12KB bq|bk|bv
  u16*   qkv = (u16*)(ws + (16u << 20) + 16384);           // 24MB Q | K | V^T bf16
  u16*   ctx = xb;                                         // overlay: xb dead after QKV GEMM

  prep_kernel<<<8195, 256, 0, stream>>>(x, Wq, Wk, Wv, Wo, bq, bk, bv, xb, wb, bc);

  // QKV: M=4096 x N=3072 -> grid 768 (bm=(bid&7)+8*((bid>>3)&3), bn=bid>>5)
  gemm_qkv<<<768, 256, 0, stream>>>(xb, wb, bc, qkv);

  // attention: 1024 blocks x 128 threads (2 waves x 32 q), 64 q/block
  attn_kernel<<<1024, 128, 0, stream>>>(qkv, qkv + 4194304, qkv + 8388608, ctx);

  // out-proj: M=4096 x N=1024, 64x128 tiles -> grid 512
  gemm_op<<<512, 256, 0, stream>>>(ctx, wb + 3 * 1048576, bo, x, out);

  ln_kernel<<<4096, 256, 0, stream>>>(out, gamma, beta);
}